// Round 4
// baseline (3365.491 us; speedup 1.0000x reference)
//
#include <hip/hip_runtime.h>
#include <hip/hip_bf16.h>

#define N_NODES 50000
#define N_EDGES 800000
#define NBASIS 10
#define NRADIAL 100
#define WNUMEL 192
#define NTILES 12500          // 800000 / 64, exact
#define EDGE_GRID 512
#define HSTRIDE 136           // shorts per h-row (128 + 8 pad; 272 B, 16B-aligned)
#define WSTRIDE 200           // shorts per w-row (192 + 8 pad)
#define SROW 160              // f32 per node in s_table: [0:64]=z0, [64:160]=z1

typedef __attribute__((ext_vector_type(8))) short short8;
typedef __attribute__((ext_vector_type(4))) float f32x4;

__device__ __forceinline__ float b2f(__hip_bfloat16 x) { return __bfloat162float(x); }
__device__ __forceinline__ float ldv(const float* p, size_t i) { return p[i]; }
__device__ __forceinline__ float ldv(const __hip_bfloat16* p, size_t i) { return b2f(p[i]); }
__device__ __forceinline__ void stv(float* p, size_t i, float v) { p[i] = v; }
__device__ __forceinline__ void stv(__hip_bfloat16* p, size_t i, float v) { p[i] = __float2bfloat16(v); }

// node_attr = ones. bf16(1.0) -> u16[0]=0x3F80 ; f32(1.0) -> u16[0]=0x0000.
__device__ __forceinline__ bool input_is_f32(const void* node_attr) {
    return ((const unsigned short*)node_attr)[0] == 0;
}

// ---------------------------------------------------------------------------
// Kernel 1: per-node linear l = fctp_scalar(x, W_l1) -> l_table (T, N x 160)
// l_table lives in d_out (exactly N*160 elements); overwritten by kernel 3.
// ---------------------------------------------------------------------------
template <class T>
__device__ __forceinline__ void node_linear_body(
    const T* __restrict__ node_input, const T* __restrict__ node_attr,
    const T* __restrict__ W_l1_0, const T* __restrict__ W_l1_1,
    T* __restrict__ l_table)
{
    int wave = (blockIdx.x * 256 + threadIdx.x) >> 6;
    int lane = threadIdx.x & 63;
    if (wave >= N_NODES) return;
    const int n = wave;
    float a = ldv(node_attr, n);
    const T* xrow = node_input + (size_t)n * 160;

    float acc = 0.f;
    for (int u = 0; u < 64; ++u)
        acc += ldv(xrow, u) * ldv(W_l1_0, u * 64 + lane);
    stv(l_table, (size_t)n * 160 + lane, acc * a * 0.125f);

    if (lane < 32) {
        float a0 = 0.f, a1 = 0.f, a2 = 0.f;
        for (int u = 0; u < 32; ++u) {
            float wv = ldv(W_l1_1, u * 32 + lane);
            a0 += ldv(xrow, 64 + u * 3 + 0) * wv;
            a1 += ldv(xrow, 64 + u * 3 + 1) * wv;
            a2 += ldv(xrow, 64 + u * 3 + 2) * wv;
        }
        const float s = a * 0.17677669529663687f;  // 1/sqrt(32)
        stv(l_table, (size_t)n * 160 + 64 + lane * 3 + 0, a0 * s);
        stv(l_table, (size_t)n * 160 + 64 + lane * 3 + 1, a1 * s);
        stv(l_table, (size_t)n * 160 + 64 + lane * 3 + 2, a2 * s);
    }
}

__global__ __launch_bounds__(256) void node_linear_kernel(
    const void* node_input, const void* node_attr,
    const void* W_l1_0, const void* W_l1_1, void* l_table)
{
    if (input_is_f32(node_attr))
        node_linear_body<float>((const float*)node_input, (const float*)node_attr,
                                (const float*)W_l1_0, (const float*)W_l1_1, (float*)l_table);
    else
        node_linear_body<__hip_bfloat16>((const __hip_bfloat16*)node_input,
                                         (const __hip_bfloat16*)node_attr,
                                         (const __hip_bfloat16*)W_l1_0,
                                         (const __hip_bfloat16*)W_l1_1,
                                         (__hip_bfloat16*)l_table);
}

// ---------------------------------------------------------------------------
// Kernel 2: edge kernel. Tile = 64 edges, block = 4 waves.
// phase0: layer1 MLP -> h (bf16, K->128) ; phase1/2: MFMA w = h @ W_fc2
// phase3: per-edge W_l2 fold (z0[64], z1[96]) + atomic scatter (160 dwords/edge)
// ---------------------------------------------------------------------------
template <class T>
__device__ __forceinline__ void edge_body(
    const T* __restrict__ edge_attr, const T* __restrict__ el,
    const T* __restrict__ W_fc1, const T* __restrict__ W_fc2,
    const T* __restrict__ W_l2_00, const T* __restrict__ W_l2_10,
    const T* __restrict__ W_l2_01, const T* __restrict__ W_l2_11,
    const int* __restrict__ edge_src, const int* __restrict__ edge_dst,
    const T* __restrict__ l_table, float* __restrict__ s_table,
    __hip_bfloat16* sW1, short* sW2B, short* sHW, float* sSt)
{
    __hip_bfloat16* sHWb = reinterpret_cast<__hip_bfloat16*>(sHW);
    const int tid = threadIdx.x;
    const int lane = tid & 63;
    const int wid = tid >> 6;
    const int quad = lane >> 4;
    const int m16 = lane & 15;
    const int wbase = wid * 16;

    // stage W_fc1 (bf16) and B-fragment-packed W_fc2 (zero-padded K 100->128)
    for (int i = tid; i < NBASIS * NRADIAL; i += 256)
        sW1[i] = __float2bfloat16(ldv(W_fc1, i));
    for (int i = tid; i < 12 * 4 * 64 * 8; i += 256) {
        int j = i & 7, ln = (i >> 3) & 63, kt = (i >> 9) & 3, t = i >> 11;
        int k = kt * 32 + ((ln >> 4) * 8) + j;
        int n = t * 16 + (ln & 15);
        reinterpret_cast<__hip_bfloat16*>(sW2B)[i] =
            (k < NRADIAL) ? __float2bfloat16(ldv(W_fc2, (size_t)k * WNUMEL + n))
                          : __float2bfloat16(0.f);
    }
    __syncthreads();

    const int e0r = tid >> 2;     // phase0 edge row (0..63)
    const int part = tid & 3;     // phase0 k-quarter

    for (int tile = blockIdx.x; tile < NTILES; tile += gridDim.x) {
        // ---- phase 0: layer-1 MLP, h' = relu(el@W1)*sqrt(2)/sqrt(10)*0.1
        {
            size_t eg = (size_t)tile * 64 + e0r;
            float elv[NBASIS];
#pragma unroll
            for (int b = 0; b < NBASIS; ++b) elv[b] = ldv(el, eg * NBASIS + b);
            const float HS = 0.04472135954999579f;
            for (int kk = 0; kk < 25; ++kk) {
                int k = part * 25 + kk;
                float z = 0.f;
#pragma unroll
                for (int b = 0; b < NBASIS; ++b)
                    z += elv[b] * b2f(sW1[b * NRADIAL + k]);
                sHWb[e0r * HSTRIDE + k] = __float2bfloat16(fmaxf(z, 0.f) * HS);
            }
            for (int k = 100 + part * 7; k < 107 + part * 7; ++k)   // pad 100..127
                sHWb[e0r * HSTRIDE + k] = __float2bfloat16(0.f);
        }
        __syncthreads();

        // ---- phase 1: A-fragment loads (wave's 16 edges)
        short8 afrag[4];
#pragma unroll
        for (int kt = 0; kt < 4; ++kt)
            afrag[kt] = *(const short8*)&sHW[(wbase + m16) * HSTRIDE + kt * 32 + quad * 8];
        __syncthreads();   // all A reads done before w-stores clobber union

        // ---- phase 2: GEMM w = h @ W2, C (bf16) into sHW rows (w layout)
#pragma unroll
        for (int t = 0; t < 12; ++t) {
            f32x4 acc = {0.f, 0.f, 0.f, 0.f};
#pragma unroll
            for (int kt = 0; kt < 4; ++kt) {
                short8 bfrag = *(const short8*)&sW2B[(((t * 4) + kt) * 64 + lane) * 8];
                acc = __builtin_amdgcn_mfma_f32_16x16x32_bf16(afrag[kt], bfrag, acc, 0, 0, 0);
            }
#pragma unroll
            for (int r = 0; r < 4; ++r) {   // C: col=lane&15, row=quad*4+r
                int er = wbase + quad * 4 + r;
                sHWb[er * WSTRIDE + t * 16 + m16] = __float2bfloat16(acc[r]);
            }
        }
        __syncthreads();

        // ---- phase 3: per-edge W_l2 fold + scatter (wave's 16 edges)
        float* sstg = sSt + wid * 256;   // per-wave staging: [0:64]=alpha,
                                         // [64:96]=delta, [96:160]=beta, [160:256]=gy
        for (int i = 0; i < 16; ++i) {
            int elc = wbase + i;
            size_t eg = (size_t)tile * 64 + elc;
            int src = edge_src[eg];
            int dst = edge_dst[eg];
            float e0  = ldv(edge_attr, eg * 4 + 0);
            float e1x = ldv(edge_attr, eg * 4 + 1);
            float e1y = ldv(edge_attr, eg * 4 + 2);
            float e1z = ldv(edge_attr, eg * 4 + 3);

            const T* lrow = l_table + (size_t)src * 160;
            float y0 = ldv(lrow, lane);
            float w_a = b2f(sHWb[elc * WSTRIDE + lane]);
            float w_b = b2f(sHWb[elc * WSTRIDE + 64 + lane]);

            sstg[lane] = w_a * y0 * e0;          // alpha
            sstg[96 + lane] = w_b * y0;          // beta
            if (lane < 32) {
                float w_c = b2f(sHWb[elc * WSTRIDE + 128 + lane]);
                float w3v = b2f(sHWb[elc * WSTRIDE + 160 + lane]);
                float y1x = ldv(lrow, 64 + lane * 3 + 0);
                float y1y = ldv(lrow, 64 + lane * 3 + 1);
                float y1z = ldv(lrow, 64 + lane * 3 + 2);
                float dot = y1x * e1x + y1y * e1y + y1z * e1z;
                sstg[64 + lane] = w3v * dot * 0.5773502691896258f;   // delta
                float g = w_c * e0;                                   // gamma
                sstg[160 + lane * 3 + 0] = g * y1x;
                sstg[160 + lane * 3 + 1] = g * y1y;
                sstg[160 + lane * 3 + 2] = g * y1z;
            }
            __syncthreads();

            // z0_j = sum_u alpha_u W00[u][j] + sum_u delta_u W10[u][j]
            float z0 = 0.f;
#pragma unroll 4
            for (int u = 0; u < 64; ++u)
                z0 += sstg[u] * ldv(W_l2_00, u * 64 + lane);
#pragma unroll 4
            for (int u = 0; u < 32; ++u)
                z0 += sstg[64 + u] * ldv(W_l2_10, u * 64 + lane);

            // lanes>=32: p_{w'} = beta @ W01 ; lanes<32: q[w'][d] = (gamma.y1) @ W11
            float p = 0.f, q0 = 0.f, q1 = 0.f, q2 = 0.f;
            if (lane >= 32) {
                int wp = lane - 32;
#pragma unroll 4
                for (int u = 0; u < 64; ++u)
                    p += sstg[96 + u] * ldv(W_l2_01, u * 32 + wp);
            } else {
#pragma unroll 4
                for (int w = 0; w < 32; ++w) {
                    float wv = ldv(W_l2_11, w * 32 + lane);
                    q0 += sstg[160 + w * 3 + 0] * wv;
                    q1 += sstg[160 + w * 3 + 1] * wv;
                    q2 += sstg[160 + w * 3 + 2] * wv;
                }
            }
            float psh = __shfl(p, lane + 32);   // lanes<32 pick up p[w'=lane]

            float* srow = s_table + (size_t)dst * SROW;
            atomicAdd(&srow[lane], z0);
            if (lane < 32) {
                atomicAdd(&srow[64 + lane * 3 + 0], psh * e1x + q0);
                atomicAdd(&srow[64 + lane * 3 + 1], psh * e1y + q1);
                atomicAdd(&srow[64 + lane * 3 + 2], psh * e1z + q2);
            }
            __syncthreads();   // staging reads done before next iter's writes
        }
        // last in-loop barrier also guards sHW before next tile's phase 0
    }
}

__global__ __launch_bounds__(256) void edge_kernel(
    const void* edge_attr, const void* el, const void* W_fc1, const void* W_fc2,
    const void* W_l2_00, const void* W_l2_10, const void* W_l2_01, const void* W_l2_11,
    const int* edge_src, const int* edge_dst, const void* l_table,
    float* s_table, const void* node_attr)
{
    __shared__ __hip_bfloat16 sW1[NBASIS * NRADIAL];   // 2000 B
    __shared__ short sW2B[12 * 4 * 64 * 8];            // 49152 B
    __shared__ short sHW[64 * WSTRIDE];                // 25600 B (h / w union)
    __shared__ float sSt[4 * 256];                     // 4096 B per-wave staging
    if (input_is_f32(node_attr))
        edge_body<float>((const float*)edge_attr, (const float*)el,
                         (const float*)W_fc1, (const float*)W_fc2,
                         (const float*)W_l2_00, (const float*)W_l2_10,
                         (const float*)W_l2_01, (const float*)W_l2_11,
                         edge_src, edge_dst, (const float*)l_table, s_table,
                         sW1, sW2B, sHW, sSt);
    else
        edge_body<__hip_bfloat16>((const __hip_bfloat16*)edge_attr,
                                  (const __hip_bfloat16*)el,
                                  (const __hip_bfloat16*)W_fc1,
                                  (const __hip_bfloat16*)W_fc2,
                                  (const __hip_bfloat16*)W_l2_00,
                                  (const __hip_bfloat16*)W_l2_10,
                                  (const __hip_bfloat16*)W_l2_01,
                                  (const __hip_bfloat16*)W_l2_11,
                                  edge_src, edge_dst,
                                  (const __hip_bfloat16*)l_table, s_table,
                                  sW1, sW2B, sHW, sSt);
}

// ---------------------------------------------------------------------------
// Kernel 3: output. out = si + OC*a*s. s_table already W_l2-mixed.
// ---------------------------------------------------------------------------
template <class T>
__device__ __forceinline__ void output_body(
    const T* __restrict__ node_input, const T* __restrict__ node_attr,
    const T* __restrict__ W_si0, const T* __restrict__ W_si1,
    const float* __restrict__ s_table, T* __restrict__ out)
{
    int wave = (blockIdx.x * 256 + threadIdx.x) >> 6;
    int lane = threadIdx.x & 63;
    if (wave >= N_NODES) return;
    const int n = wave;
    float a = ldv(node_attr, n);
    const T* xrow = node_input + (size_t)n * 160;
    const float* srow = s_table + (size_t)n * SROW;

    // 0.5 (skip-mix) * 0.25 (1/sqrt(16)) / sqrt(96)
    const float OC = 0.5f * 0.25f / 9.797958971132712f;

    float si = 0.f;
    for (int u = 0; u < 64; ++u)
        si += ldv(xrow, u) * ldv(W_si0, u * 64 + lane);
    stv(out, (size_t)n * 160 + lane, si * a * 0.125f + srow[lane] * a * OC);

    if (lane < 32) {
        float sid[3] = {0.f, 0.f, 0.f};
        for (int u = 0; u < 32; ++u) {
            float wsi = ldv(W_si1, u * 32 + lane);
#pragma unroll
            for (int d = 0; d < 3; ++d)
                sid[d] += ldv(xrow, 64 + u * 3 + d) * wsi;
        }
        const float SI1 = a * 0.17677669529663687f;       // a/sqrt(32)
#pragma unroll
        for (int d = 0; d < 3; ++d)
            stv(out, (size_t)n * 160 + 64 + lane * 3 + d,
                sid[d] * SI1 + srow[64 + lane * 3 + d] * a * OC);
    }
}

__global__ __launch_bounds__(256) void output_kernel(
    const void* node_input, const void* node_attr,
    const void* W_si0, const void* W_si1,
    const float* s_table, void* out)
{
    if (input_is_f32(node_attr))
        output_body<float>((const float*)node_input, (const float*)node_attr,
                           (const float*)W_si0, (const float*)W_si1,
                           s_table, (float*)out);
    else
        output_body<__hip_bfloat16>((const __hip_bfloat16*)node_input,
                                    (const __hip_bfloat16*)node_attr,
                                    (const __hip_bfloat16*)W_si0,
                                    (const __hip_bfloat16*)W_si1,
                                    s_table, (__hip_bfloat16*)out);
}

extern "C" void kernel_launch(void* const* d_in, const int* in_sizes, int n_in,
                              void* d_out, int out_size, void* d_ws, size_t ws_size,
                              hipStream_t stream)
{
    const void* node_input = d_in[0];
    const void* node_attr  = d_in[1];
    const void* edge_attr  = d_in[2];
    const void* el         = d_in[3];
    const void* W_si0  = d_in[4];
    const void* W_si1  = d_in[5];
    const void* W_l1_0 = d_in[6];
    const void* W_l1_1 = d_in[7];
    const void* W_l2_00 = d_in[8];
    const void* W_l2_10 = d_in[9];
    const void* W_l2_01 = d_in[10];
    const void* W_l2_11 = d_in[11];
    const void* W_fc1  = d_in[12];
    const void* W_fc2  = d_in[13];
    const int* edge_src = (const int*)d_in[14];
    const int* edge_dst = (const int*)d_in[15];

    // ws: s_table only (N*160 f32 = 32 MB). l_table lives in d_out.
    float* s_table = (float*)d_ws;
    void* l_table = d_out;

    hipMemsetAsync(s_table, 0, (size_t)N_NODES * SROW * sizeof(float), stream);
    node_linear_kernel<<<(N_NODES + 3) / 4, 256, 0, stream>>>(
        node_input, node_attr, W_l1_0, W_l1_1, l_table);
    edge_kernel<<<EDGE_GRID, 256, 0, stream>>>(
        edge_attr, el, W_fc1, W_fc2, W_l2_00, W_l2_10, W_l2_01, W_l2_11,
        edge_src, edge_dst, l_table, s_table, node_attr);
    output_kernel<<<(N_NODES + 3) / 4, 256, 0, stream>>>(
        node_input, node_attr, W_si0, W_si1, s_table, d_out);
}

// Round 5
// 1491.149 us; speedup vs baseline: 2.2570x; 2.2570x over previous
//
#include <hip/hip_runtime.h>
#include <hip/hip_bf16.h>

#define N_NODES 50000
#define N_EDGES 800000
#define NBASIS 10
#define NRADIAL 100
#define WNUMEL 192
#define NTILES 12500          // 800000 / 64, exact
#define EDGE_GRID 512
#define HSTRIDE 136           // shorts per h-row (128 + 8 pad; 272 B, 16B-aligned)
#define WSTRIDE 200           // shorts per w-row (192 + 8 pad)
// s_table: bf16, 384 per node, plane layout:
// [0:64]=s0 | [64:128]=s1x [128:192]=s1y [192:256]=s1z
// [256:288]=s2x [288:320]=s2y [320:352]=s2z | [352:384]=s3

typedef __attribute__((ext_vector_type(8))) short short8;
typedef __attribute__((ext_vector_type(4))) float f32x4;

__device__ __forceinline__ float b2f(__hip_bfloat16 x) { return __bfloat162float(x); }
__device__ __forceinline__ float ldv(const float* p, size_t i) { return p[i]; }
__device__ __forceinline__ float ldv(const __hip_bfloat16* p, size_t i) { return b2f(p[i]); }
__device__ __forceinline__ void stv(float* p, size_t i, float v) { p[i] = v; }
__device__ __forceinline__ void stv(__hip_bfloat16* p, size_t i, float v) { p[i] = __float2bfloat16(v); }

__device__ __forceinline__ bool input_is_f32(const void* node_attr) {
    return ((const unsigned short*)node_attr)[0] == 0;   // bf16(1.0)=0x3F80
}

__device__ __forceinline__ unsigned int pack_bf2(float x, float y) {
    __hip_bfloat162 h;
    h.x = __float2bfloat16(x);
    h.y = __float2bfloat16(y);
    unsigned int u;
    __builtin_memcpy(&u, &h, 4);
    return u;
}

__device__ __forceinline__ void pk_atomic_bf16(__hip_bfloat16* addr, unsigned int data) {
    asm volatile("global_atomic_pk_add_bf16 %0, %1, off"
                 :: "v"((unsigned long long)(uintptr_t)addr), "v"(data)
                 : "memory");
}

// ---------------------------------------------------------------------------
// Sort kernels: counting sort of edges by dst.
// ---------------------------------------------------------------------------
__global__ __launch_bounds__(256) void hist_kernel(const int* __restrict__ edge_dst,
                                                   int* __restrict__ counts) {
    int i = blockIdx.x * 256 + threadIdx.x;
    if (i < N_EDGES) atomicAdd(&counts[edge_dst[i]], 1);
}

__global__ __launch_bounds__(1024) void scan_kernel(int* __restrict__ counts) {
    __shared__ int lsum[1024];
    int t = threadIdx.x;
    int lo = t * 49;
    int hi = min(lo + 49, N_NODES);
    int s = 0;
    for (int i = lo; i < hi; ++i) s += counts[i];
    lsum[t] = s;
    __syncthreads();
    for (int off = 1; off < 1024; off <<= 1) {
        int add = (t >= off) ? lsum[t - off] : 0;
        __syncthreads();
        lsum[t] += add;
        __syncthreads();
    }
    int running = lsum[t] - s;   // exclusive prefix
    for (int i = lo; i < hi; ++i) { int c = counts[i]; counts[i] = running; running += c; }
}

__global__ __launch_bounds__(256) void scatter_kernel(const int* __restrict__ edge_dst,
                                                      int* __restrict__ counts,
                                                      int* __restrict__ sorted_idx) {
    int i = blockIdx.x * 256 + threadIdx.x;
    if (i < N_EDGES) {
        int p = atomicAdd(&counts[edge_dst[i]], 1);
        sorted_idx[p] = i;
    }
}

// ---------------------------------------------------------------------------
// Kernel 1: per-node linear l = fctp_scalar(x, W_l1) -> l_table (T, N x 160)
// l_table lives in d_out; overwritten by kernel 3.
// ---------------------------------------------------------------------------
template <class T>
__device__ __forceinline__ void node_linear_body(
    const T* __restrict__ node_input, const T* __restrict__ node_attr,
    const T* __restrict__ W_l1_0, const T* __restrict__ W_l1_1,
    T* __restrict__ l_table)
{
    int wave = (blockIdx.x * 256 + threadIdx.x) >> 6;
    int lane = threadIdx.x & 63;
    if (wave >= N_NODES) return;
    const int n = wave;
    float a = ldv(node_attr, n);
    const T* xrow = node_input + (size_t)n * 160;

    float acc = 0.f;
    for (int u = 0; u < 64; ++u)
        acc += ldv(xrow, u) * ldv(W_l1_0, u * 64 + lane);
    stv(l_table, (size_t)n * 160 + lane, acc * a * 0.125f);

    if (lane < 32) {
        float a0 = 0.f, a1 = 0.f, a2 = 0.f;
        for (int u = 0; u < 32; ++u) {
            float wv = ldv(W_l1_1, u * 32 + lane);
            a0 += ldv(xrow, 64 + u * 3 + 0) * wv;
            a1 += ldv(xrow, 64 + u * 3 + 1) * wv;
            a2 += ldv(xrow, 64 + u * 3 + 2) * wv;
        }
        const float s = a * 0.17677669529663687f;  // 1/sqrt(32)
        stv(l_table, (size_t)n * 160 + 64 + lane * 3 + 0, a0 * s);
        stv(l_table, (size_t)n * 160 + 64 + lane * 3 + 1, a1 * s);
        stv(l_table, (size_t)n * 160 + 64 + lane * 3 + 2, a2 * s);
    }
}

__global__ __launch_bounds__(256) void node_linear_kernel(
    const void* node_input, const void* node_attr,
    const void* W_l1_0, const void* W_l1_1, void* l_table)
{
    if (input_is_f32(node_attr))
        node_linear_body<float>((const float*)node_input, (const float*)node_attr,
                                (const float*)W_l1_0, (const float*)W_l1_1, (float*)l_table);
    else
        node_linear_body<__hip_bfloat16>((const __hip_bfloat16*)node_input,
                                         (const __hip_bfloat16*)node_attr,
                                         (const __hip_bfloat16*)W_l1_0,
                                         (const __hip_bfloat16*)W_l1_1,
                                         (__hip_bfloat16*)l_table);
}

// ---------------------------------------------------------------------------
// flush: pk-bf16 atomic add of 8 accumulator components into s_table[dst].
// Pairs formed across (even,odd) lane neighbors via shfl_down.
// ---------------------------------------------------------------------------
__device__ __forceinline__ void flush_acc(
    __hip_bfloat16* __restrict__ s_table, int dst, int lane,
    float A0, float A1x, float A1y, float A1z,
    float A2x, float A2y, float A2z, float A3)
{
    if (dst < 0) return;
    __hip_bfloat16* srow = s_table + (size_t)dst * 384;
    float B0  = __shfl_down(A0, 1);
    float B1x = __shfl_down(A1x, 1);
    float B1y = __shfl_down(A1y, 1);
    float B1z = __shfl_down(A1z, 1);
    float B2x = __shfl_down(A2x, 1);
    float B2y = __shfl_down(A2y, 1);
    float B2z = __shfl_down(A2z, 1);
    float B3  = __shfl_down(A3, 1);
    if ((lane & 1) == 0) {
        pk_atomic_bf16(srow + lane,        pack_bf2(A0, B0));
        pk_atomic_bf16(srow + 64 + lane,   pack_bf2(A1x, B1x));
        pk_atomic_bf16(srow + 128 + lane,  pack_bf2(A1y, B1y));
        pk_atomic_bf16(srow + 192 + lane,  pack_bf2(A1z, B1z));
        if (lane < 32) {
            pk_atomic_bf16(srow + 256 + lane, pack_bf2(A2x, B2x));
            pk_atomic_bf16(srow + 288 + lane, pack_bf2(A2y, B2y));
            pk_atomic_bf16(srow + 320 + lane, pack_bf2(A2z, B2z));
            pk_atomic_bf16(srow + 352 + lane, pack_bf2(A3, B3));
        }
    }
}

// ---------------------------------------------------------------------------
// Kernel 2: edge kernel over SORTED edges. Tile = 64 edges, block = 4 waves.
// phase0: layer1 MLP -> h (bf16, K->128); phase1/2: MFMA w = h @ W_fc2;
// phase3: per-wave run-aggregated messages, pk-bf16 atomic flush on dst change.
// ---------------------------------------------------------------------------
template <class T>
__device__ __forceinline__ void edge_body(
    const T* __restrict__ edge_attr, const T* __restrict__ el,
    const T* __restrict__ W_fc1, const T* __restrict__ W_fc2,
    const int* __restrict__ edge_src, const int* __restrict__ edge_dst,
    const int* __restrict__ sorted_idx,
    const T* __restrict__ l_table, __hip_bfloat16* __restrict__ s_table,
    __hip_bfloat16* sW1, short* sW2B, short* sHW)
{
    __hip_bfloat16* sHWb = reinterpret_cast<__hip_bfloat16*>(sHW);
    const int tid = threadIdx.x;
    const int lane = tid & 63;
    const int wid = tid >> 6;
    const int quad = lane >> 4;
    const int m16 = lane & 15;
    const int wbase = wid * 16;

    for (int i = tid; i < NBASIS * NRADIAL; i += 256)
        sW1[i] = __float2bfloat16(ldv(W_fc1, i));
    for (int i = tid; i < 12 * 4 * 64 * 8; i += 256) {
        int j = i & 7, ln = (i >> 3) & 63, kt = (i >> 9) & 3, t = i >> 11;
        int k = kt * 32 + ((ln >> 4) * 8) + j;
        int n = t * 16 + (ln & 15);
        reinterpret_cast<__hip_bfloat16*>(sW2B)[i] =
            (k < NRADIAL) ? __float2bfloat16(ldv(W_fc2, (size_t)k * WNUMEL + n))
                          : __float2bfloat16(0.f);
    }
    __syncthreads();

    const int e0r = tid >> 2;     // phase0 edge row (0..63)
    const int part = tid & 3;     // phase0 k-quarter

    for (int tile = blockIdx.x; tile < NTILES; tile += gridDim.x) {
        // ---- phase 0: layer-1 MLP on sorted edge e0r
        {
            int eg = sorted_idx[tile * 64 + e0r];
            float elv[NBASIS];
#pragma unroll
            for (int b = 0; b < NBASIS; ++b) elv[b] = ldv(el, (size_t)eg * NBASIS + b);
            const float HS = 0.04472135954999579f;   // sqrt(2)/sqrt(10)*0.1
            for (int kk = 0; kk < 25; ++kk) {
                int k = part * 25 + kk;
                float z = 0.f;
#pragma unroll
                for (int b = 0; b < NBASIS; ++b)
                    z += elv[b] * b2f(sW1[b * NRADIAL + k]);
                sHWb[e0r * HSTRIDE + k] = __float2bfloat16(fmaxf(z, 0.f) * HS);
            }
            for (int k = 100 + part * 7; k < 107 + part * 7; ++k)   // pad 100..127
                sHWb[e0r * HSTRIDE + k] = __float2bfloat16(0.f);
        }
        __syncthreads();

        // ---- phase 1: A-fragment loads (wave's 16 edges)
        short8 afrag[4];
#pragma unroll
        for (int kt = 0; kt < 4; ++kt)
            afrag[kt] = *(const short8*)&sHW[(wbase + m16) * HSTRIDE + kt * 32 + quad * 8];
        __syncthreads();

        // ---- phase 2: GEMM w = h @ W2, C (bf16) into sHW rows
#pragma unroll
        for (int t = 0; t < 12; ++t) {
            f32x4 acc = {0.f, 0.f, 0.f, 0.f};
#pragma unroll
            for (int kt = 0; kt < 4; ++kt) {
                short8 bfrag = *(const short8*)&sW2B[(((t * 4) + kt) * 64 + lane) * 8];
                acc = __builtin_amdgcn_mfma_f32_16x16x32_bf16(afrag[kt], bfrag, acc, 0, 0, 0);
            }
#pragma unroll
            for (int r = 0; r < 4; ++r) {
                int er = wbase + quad * 4 + r;
                sHWb[er * WSTRIDE + t * 16 + m16] = __float2bfloat16(acc[r]);
            }
        }
        __syncthreads();

        // ---- phase 3: run-aggregated messages + pk-bf16 atomic scatter
        float A0 = 0.f, A1x = 0.f, A1y = 0.f, A1z = 0.f;
        float A2x = 0.f, A2y = 0.f, A2z = 0.f, A3 = 0.f;
        int cur_dst = -1;
        for (int i = 0; i < 16; ++i) {
            int elc = wbase + i;
            int eg = sorted_idx[tile * 64 + elc];      // wave-uniform
            int dst = edge_dst[eg];                    // wave-uniform
            if (dst != cur_dst) {
                flush_acc(s_table, cur_dst, lane, A0, A1x, A1y, A1z, A2x, A2y, A2z, A3);
                A0 = A1x = A1y = A1z = A2x = A2y = A2z = A3 = 0.f;
                cur_dst = dst;
            }
            int src = edge_src[eg];
            float e0  = ldv(edge_attr, (size_t)eg * 4 + 0);
            float e1x = ldv(edge_attr, (size_t)eg * 4 + 1);
            float e1y = ldv(edge_attr, (size_t)eg * 4 + 2);
            float e1z = ldv(edge_attr, (size_t)eg * 4 + 3);

            const T* lrow = l_table + (size_t)src * 160;
            float y0 = ldv(lrow, lane);
            float w_a = b2f(sHWb[elc * WSTRIDE + lane]);
            float w_b = b2f(sHWb[elc * WSTRIDE + 64 + lane]);

            A0 += w_a * y0 * e0;                       // m0
            float m1b = w_b * y0;                      // m1
            A1x += m1b * e1x; A1y += m1b * e1y; A1z += m1b * e1z;
            if (lane < 32) {
                float w_c = b2f(sHWb[elc * WSTRIDE + 128 + lane]);
                float w3v = b2f(sHWb[elc * WSTRIDE + 160 + lane]);
                float y1x = ldv(lrow, 64 + lane * 3 + 0);
                float y1y = ldv(lrow, 64 + lane * 3 + 1);
                float y1z = ldv(lrow, 64 + lane * 3 + 2);
                float g = w_c * e0;                    // m2
                A2x += g * y1x; A2y += g * y1y; A2z += g * y1z;
                float dot = y1x * e1x + y1y * e1y + y1z * e1z;
                A3 += w3v * dot * 0.5773502691896258f; // m3
            }
        }
        flush_acc(s_table, cur_dst, lane, A0, A1x, A1y, A1z, A2x, A2y, A2z, A3);
        __syncthreads();   // sHW reads done before next tile's phase 0
    }
    asm volatile("s_waitcnt vmcnt(0)" ::: "memory");   // drain asm atomics
}

__global__ __launch_bounds__(256) void edge_kernel(
    const void* edge_attr, const void* el, const void* W_fc1, const void* W_fc2,
    const int* edge_src, const int* edge_dst, const int* sorted_idx,
    const void* l_table, __hip_bfloat16* s_table, const void* node_attr)
{
    __shared__ __hip_bfloat16 sW1[NBASIS * NRADIAL];   // 2000 B
    __shared__ short sW2B[12 * 4 * 64 * 8];            // 49152 B
    __shared__ short sHW[64 * WSTRIDE];                // 25600 B (h / w union)
    if (input_is_f32(node_attr))
        edge_body<float>((const float*)edge_attr, (const float*)el,
                         (const float*)W_fc1, (const float*)W_fc2,
                         edge_src, edge_dst, sorted_idx,
                         (const float*)l_table, s_table, sW1, sW2B, sHW);
    else
        edge_body<__hip_bfloat16>((const __hip_bfloat16*)edge_attr,
                                  (const __hip_bfloat16*)el,
                                  (const __hip_bfloat16*)W_fc1,
                                  (const __hip_bfloat16*)W_fc2,
                                  edge_src, edge_dst, sorted_idx,
                                  (const __hip_bfloat16*)l_table, s_table,
                                  sW1, sW2B, sHW);
}

// ---------------------------------------------------------------------------
// Kernel 3: output. Per-node W_l2 mixes of bf16 s_table + self-interaction.
// ---------------------------------------------------------------------------
template <class T>
__device__ __forceinline__ void output_body(
    const T* __restrict__ node_input, const T* __restrict__ node_attr,
    const T* __restrict__ W_si0, const T* __restrict__ W_si1,
    const T* __restrict__ W_l2_00, const T* __restrict__ W_l2_10,
    const T* __restrict__ W_l2_01, const T* __restrict__ W_l2_11,
    const __hip_bfloat16* __restrict__ s_table, T* __restrict__ out)
{
    int wave = (blockIdx.x * 256 + threadIdx.x) >> 6;
    int lane = threadIdx.x & 63;
    if (wave >= N_NODES) return;
    const int n = wave;
    float a = ldv(node_attr, n);
    const T* xrow = node_input + (size_t)n * 160;
    const __hip_bfloat16* srow = s_table + (size_t)n * 384;

    float si = 0.f, o = 0.f;
    for (int u = 0; u < 64; ++u) {
        si += ldv(xrow, u) * ldv(W_si0, u * 64 + lane);
        o += b2f(srow[u]) * ldv(W_l2_00, u * 64 + lane);
    }
    for (int u = 0; u < 32; ++u)
        o += b2f(srow[352 + u]) * ldv(W_l2_10, u * 64 + lane);

    // 0.5 (skip-mix) * 0.25 (1/sqrt(16)) / sqrt(96)
    const float OC = 0.5f * 0.25f / 9.797958971132712f;
    stv(out, (size_t)n * 160 + lane, si * a * 0.125f + o * a * OC);

    if (lane < 32) {
        float sid[3] = {0.f, 0.f, 0.f}, od[3] = {0.f, 0.f, 0.f};
        for (int u = 0; u < 32; ++u) {
            float wsi = ldv(W_si1, u * 32 + lane);
            float wl2 = ldv(W_l2_11, u * 32 + lane);
#pragma unroll
            for (int d = 0; d < 3; ++d) {
                sid[d] += ldv(xrow, 64 + u * 3 + d) * wsi;
                od[d] += b2f(srow[256 + d * 32 + u]) * wl2;   // s2 planes
            }
        }
        for (int u = 0; u < 64; ++u) {
            float wl2 = ldv(W_l2_01, u * 32 + lane);
#pragma unroll
            for (int d = 0; d < 3; ++d)
                od[d] += b2f(srow[64 + d * 64 + u]) * wl2;    // s1 planes
        }
        const float SI1 = a * 0.17677669529663687f;
#pragma unroll
        for (int d = 0; d < 3; ++d)
            stv(out, (size_t)n * 160 + 64 + lane * 3 + d, sid[d] * SI1 + od[d] * a * OC);
    }
}

__global__ __launch_bounds__(256) void output_kernel(
    const void* node_input, const void* node_attr,
    const void* W_si0, const void* W_si1,
    const void* W_l2_00, const void* W_l2_10,
    const void* W_l2_01, const void* W_l2_11,
    const __hip_bfloat16* s_table, void* out)
{
    if (input_is_f32(node_attr))
        output_body<float>((const float*)node_input, (const float*)node_attr,
                           (const float*)W_si0, (const float*)W_si1,
                           (const float*)W_l2_00, (const float*)W_l2_10,
                           (const float*)W_l2_01, (const float*)W_l2_11,
                           s_table, (float*)out);
    else
        output_body<__hip_bfloat16>((const __hip_bfloat16*)node_input,
                                    (const __hip_bfloat16*)node_attr,
                                    (const __hip_bfloat16*)W_si0,
                                    (const __hip_bfloat16*)W_si1,
                                    (const __hip_bfloat16*)W_l2_00,
                                    (const __hip_bfloat16*)W_l2_10,
                                    (const __hip_bfloat16*)W_l2_01,
                                    (const __hip_bfloat16*)W_l2_11,
                                    s_table, (__hip_bfloat16*)out);
}

extern "C" void kernel_launch(void* const* d_in, const int* in_sizes, int n_in,
                              void* d_out, int out_size, void* d_ws, size_t ws_size,
                              hipStream_t stream)
{
    const void* node_input = d_in[0];
    const void* node_attr  = d_in[1];
    const void* edge_attr  = d_in[2];
    const void* el         = d_in[3];
    const void* W_si0  = d_in[4];
    const void* W_si1  = d_in[5];
    const void* W_l1_0 = d_in[6];
    const void* W_l1_1 = d_in[7];
    const void* W_l2_00 = d_in[8];
    const void* W_l2_10 = d_in[9];
    const void* W_l2_01 = d_in[10];
    const void* W_l2_11 = d_in[11];
    const void* W_fc1  = d_in[12];
    const void* W_fc2  = d_in[13];
    const int* edge_src = (const int*)d_in[14];
    const int* edge_dst = (const int*)d_in[15];

    // ws layout: s_table bf16 (N*384*2 = 38.4 MB) | sorted_idx (3.2 MB) | counts (0.2 MB)
    __hip_bfloat16* s_table = (__hip_bfloat16*)d_ws;
    int* sorted_idx = (int*)((char*)d_ws + (size_t)N_NODES * 384 * 2);
    int* counts     = (int*)((char*)sorted_idx + (size_t)N_EDGES * 4);
    void* l_table = d_out;   // N*160 elements, overwritten by output_kernel

    size_t ws_used = (size_t)N_NODES * 384 * 2 + (size_t)N_EDGES * 4 + (size_t)N_NODES * 4;
    hipMemsetAsync(d_ws, 0, ws_used, stream);

    hist_kernel<<<(N_EDGES + 255) / 256, 256, 0, stream>>>(edge_dst, counts);
    scan_kernel<<<1, 1024, 0, stream>>>(counts);
    scatter_kernel<<<(N_EDGES + 255) / 256, 256, 0, stream>>>(edge_dst, counts, sorted_idx);

    node_linear_kernel<<<(N_NODES + 3) / 4, 256, 0, stream>>>(
        node_input, node_attr, W_l1_0, W_l1_1, l_table);
    edge_kernel<<<EDGE_GRID, 256, 0, stream>>>(
        edge_attr, el, W_fc1, W_fc2, edge_src, edge_dst, sorted_idx,
        l_table, s_table, node_attr);
    output_kernel<<<(N_NODES + 3) / 4, 256, 0, stream>>>(
        node_input, node_attr, W_si0, W_si1, W_l2_00, W_l2_10, W_l2_01, W_l2_11,
        s_table, d_out);
}

// Round 7
// 1250.799 us; speedup vs baseline: 2.6907x; 1.1922x over previous
//
#include <hip/hip_runtime.h>
#include <hip/hip_bf16.h>

#define N_NODES 50000
#define N_EDGES 800000
#define NBASIS 10
#define NRADIAL 100
#define WNUMEL 192
#define NTILES 12500          // 800000 / 64, exact
#define EDGE_GRID 512
#define HSTRIDE 136           // shorts per h-row (128 + 8 pad; 272 B, 16B-aligned)
#define WSTRIDE 200           // shorts per w-row (192 + 8 pad)
// s_table: bf16, 384 per node, plane layout:
// [0:64]=s0 | [64:128]=s1x [128:192]=s1y [192:256]=s1z
// [256:288]=s2x [288:320]=s2y [320:352]=s2z | [352:384]=s3

typedef __attribute__((ext_vector_type(8))) short short8;
typedef __attribute__((ext_vector_type(4))) float f32x4;

__device__ __forceinline__ float b2f(__hip_bfloat16 x) { return __bfloat162float(x); }
__device__ __forceinline__ float ldv(const float* p, size_t i) { return p[i]; }
__device__ __forceinline__ float ldv(const __hip_bfloat16* p, size_t i) { return b2f(p[i]); }
__device__ __forceinline__ void stv(float* p, size_t i, float v) { p[i] = v; }
__device__ __forceinline__ void stv(__hip_bfloat16* p, size_t i, float v) { p[i] = __float2bfloat16(v); }

__device__ __forceinline__ bool input_is_f32(const void* node_attr) {
    return ((const unsigned short*)node_attr)[0] == 0;   // bf16(1.0)=0x3F80
}

__device__ __forceinline__ unsigned int pack_bf2(float x, float y) {
    __hip_bfloat162 h;
    h.x = __float2bfloat16(x);
    h.y = __float2bfloat16(y);
    unsigned int u;
    __builtin_memcpy(&u, &h, 4);
    return u;
}

__device__ __forceinline__ void pk_atomic_bf16(__hip_bfloat16* addr, unsigned int data) {
    asm volatile("global_atomic_pk_add_bf16 %0, %1, off"
                 :: "v"((unsigned long long)(uintptr_t)addr), "v"(data)
                 : "memory");
}

// ---------------------------------------------------------------------------
// Sort kernels: counting sort of edges by dst.  (R5 known-good versions.)
// ---------------------------------------------------------------------------
__global__ __launch_bounds__(256) void hist_kernel(const int* __restrict__ edge_dst,
                                                   int* __restrict__ counts) {
    int i = blockIdx.x * 256 + threadIdx.x;
    if (i < N_EDGES) atomicAdd(&counts[edge_dst[i]], 1);
}

__global__ __launch_bounds__(1024) void scan_kernel(int* __restrict__ counts) {
    __shared__ int lsum[1024];
    int t = threadIdx.x;
    int lo = t * 49;
    int hi = min(lo + 49, N_NODES);
    int s = 0;
    for (int i = lo; i < hi; ++i) s += counts[i];
    lsum[t] = s;
    __syncthreads();
    for (int off = 1; off < 1024; off <<= 1) {
        int add = (t >= off) ? lsum[t - off] : 0;
        __syncthreads();
        lsum[t] += add;
        __syncthreads();
    }
    int running = lsum[t] - s;   // exclusive prefix
    for (int i = lo; i < hi; ++i) { int c = counts[i]; counts[i] = running; running += c; }
}

__global__ __launch_bounds__(256) void scatter_kernel(const int* __restrict__ edge_dst,
                                                      int* __restrict__ counts,
                                                      int* __restrict__ sorted_idx) {
    int i = blockIdx.x * 256 + threadIdx.x;
    if (i < N_EDGES) {
        int p = atomicAdd(&counts[edge_dst[i]], 1);
        sorted_idx[p] = i;
    }
}

// ---------------------------------------------------------------------------
// Kernel 1: per-node linear l = fctp_scalar(x, W_l1) -> l_table (T, N x 160)
// l_table lives in d_out; overwritten by kernel 3.
// ---------------------------------------------------------------------------
template <class T>
__device__ __forceinline__ void node_linear_body(
    const T* __restrict__ node_input, const T* __restrict__ node_attr,
    const T* __restrict__ W_l1_0, const T* __restrict__ W_l1_1,
    T* __restrict__ l_table)
{
    int wave = (blockIdx.x * 256 + threadIdx.x) >> 6;
    int lane = threadIdx.x & 63;
    if (wave >= N_NODES) return;
    const int n = wave;
    float a = ldv(node_attr, n);
    const T* xrow = node_input + (size_t)n * 160;

    float acc = 0.f;
    for (int u = 0; u < 64; ++u)
        acc += ldv(xrow, u) * ldv(W_l1_0, u * 64 + lane);
    stv(l_table, (size_t)n * 160 + lane, acc * a * 0.125f);

    if (lane < 32) {
        float a0 = 0.f, a1 = 0.f, a2 = 0.f;
        for (int u = 0; u < 32; ++u) {
            float wv = ldv(W_l1_1, u * 32 + lane);
            a0 += ldv(xrow, 64 + u * 3 + 0) * wv;
            a1 += ldv(xrow, 64 + u * 3 + 1) * wv;
            a2 += ldv(xrow, 64 + u * 3 + 2) * wv;
        }
        const float s = a * 0.17677669529663687f;  // 1/sqrt(32)
        stv(l_table, (size_t)n * 160 + 64 + lane * 3 + 0, a0 * s);
        stv(l_table, (size_t)n * 160 + 64 + lane * 3 + 1, a1 * s);
        stv(l_table, (size_t)n * 160 + 64 + lane * 3 + 2, a2 * s);
    }
}

__global__ __launch_bounds__(256) void node_linear_kernel(
    const void* node_input, const void* node_attr,
    const void* W_l1_0, const void* W_l1_1, void* l_table)
{
    if (input_is_f32(node_attr))
        node_linear_body<float>((const float*)node_input, (const float*)node_attr,
                                (const float*)W_l1_0, (const float*)W_l1_1, (float*)l_table);
    else
        node_linear_body<__hip_bfloat16>((const __hip_bfloat16*)node_input,
                                         (const __hip_bfloat16*)node_attr,
                                         (const __hip_bfloat16*)W_l1_0,
                                         (const __hip_bfloat16*)W_l1_1,
                                         (__hip_bfloat16*)l_table);
}

// ---------------------------------------------------------------------------
// flush: pk-bf16 atomic add of 8 accumulator components into s_table[dst].
// ---------------------------------------------------------------------------
__device__ __forceinline__ void flush_acc(
    __hip_bfloat16* __restrict__ s_table, int dst, int lane,
    float A0, float A1x, float A1y, float A1z,
    float A2x, float A2y, float A2z, float A3)
{
    if (dst < 0) return;
    __hip_bfloat16* srow = s_table + (size_t)dst * 384;
    float B0  = __shfl_down(A0, 1);
    float B1x = __shfl_down(A1x, 1);
    float B1y = __shfl_down(A1y, 1);
    float B1z = __shfl_down(A1z, 1);
    float B2x = __shfl_down(A2x, 1);
    float B2y = __shfl_down(A2y, 1);
    float B2z = __shfl_down(A2z, 1);
    float B3  = __shfl_down(A3, 1);
    if ((lane & 1) == 0) {
        pk_atomic_bf16(srow + lane,        pack_bf2(A0, B0));
        pk_atomic_bf16(srow + 64 + lane,   pack_bf2(A1x, B1x));
        pk_atomic_bf16(srow + 128 + lane,  pack_bf2(A1y, B1y));
        pk_atomic_bf16(srow + 192 + lane,  pack_bf2(A1z, B1z));
        if (lane < 32) {
            pk_atomic_bf16(srow + 256 + lane, pack_bf2(A2x, B2x));
            pk_atomic_bf16(srow + 288 + lane, pack_bf2(A2y, B2y));
            pk_atomic_bf16(srow + 320 + lane, pack_bf2(A2z, B2z));
            pk_atomic_bf16(srow + 352 + lane, pack_bf2(A3, B3));
        }
    }
}

// ---------------------------------------------------------------------------
// Kernel 2: edge kernel over SORTED edges (R5 structure, one change:
// tile metadata src/dst/attr pre-staged into LDS during phase 0, so the
// phase-3 serial chain is LDS->gather instead of 3 chained global loads).
// ---------------------------------------------------------------------------
template <class T>
__device__ __forceinline__ void edge_body(
    const T* __restrict__ edge_attr, const T* __restrict__ el,
    const T* __restrict__ W_fc1, const T* __restrict__ W_fc2,
    const int* __restrict__ edge_src, const int* __restrict__ edge_dst,
    const int* __restrict__ sorted_idx,
    const T* __restrict__ l_table, __hip_bfloat16* __restrict__ s_table,
    __hip_bfloat16* sW1, short* sW2B, short* sHW,
    int* sSrc, int* sDst, float* sAttr)
{
    __hip_bfloat16* sHWb = reinterpret_cast<__hip_bfloat16*>(sHW);
    const int tid = threadIdx.x;
    const int lane = tid & 63;
    const int wid = tid >> 6;
    const int quad = lane >> 4;
    const int m16 = lane & 15;
    const int wbase = wid * 16;

    for (int i = tid; i < NBASIS * NRADIAL; i += 256)
        sW1[i] = __float2bfloat16(ldv(W_fc1, i));
    for (int i = tid; i < 12 * 4 * 64 * 8; i += 256) {
        int j = i & 7, ln = (i >> 3) & 63, kt = (i >> 9) & 3, t = i >> 11;
        int k = kt * 32 + ((ln >> 4) * 8) + j;
        int n = t * 16 + (ln & 15);
        reinterpret_cast<__hip_bfloat16*>(sW2B)[i] =
            (k < NRADIAL) ? __float2bfloat16(ldv(W_fc2, (size_t)k * WNUMEL + n))
                          : __float2bfloat16(0.f);
    }
    __syncthreads();

    const int e0r = tid >> 2;     // phase0 edge row (0..63)
    const int part = tid & 3;     // phase0 k-quarter

    for (int tile = blockIdx.x; tile < NTILES; tile += gridDim.x) {
        const int eg = sorted_idx[tile * 64 + e0r];

        // ---- metadata pre-stage (covered by the phase-0 barrier)
        if (part == 0)      sSrc[e0r] = edge_src[eg];
        else if (part == 1) sDst[e0r] = edge_dst[eg];
        else if (part == 2) {
            sAttr[e0r * 4 + 0] = ldv(edge_attr, (size_t)eg * 4 + 0);
            sAttr[e0r * 4 + 1] = ldv(edge_attr, (size_t)eg * 4 + 1);
        } else {
            sAttr[e0r * 4 + 2] = ldv(edge_attr, (size_t)eg * 4 + 2);
            sAttr[e0r * 4 + 3] = ldv(edge_attr, (size_t)eg * 4 + 3);
        }

        // ---- phase 0: layer-1 MLP on sorted edge e0r
        {
            float elv[NBASIS];
#pragma unroll
            for (int b = 0; b < NBASIS; ++b) elv[b] = ldv(el, (size_t)eg * NBASIS + b);
            const float HS = 0.04472135954999579f;   // sqrt(2)/sqrt(10)*0.1
            for (int kk = 0; kk < 25; ++kk) {
                int k = part * 25 + kk;
                float z = 0.f;
#pragma unroll
                for (int b = 0; b < NBASIS; ++b)
                    z += elv[b] * b2f(sW1[b * NRADIAL + k]);
                sHWb[e0r * HSTRIDE + k] = __float2bfloat16(fmaxf(z, 0.f) * HS);
            }
            for (int k = 100 + part * 7; k < 107 + part * 7; ++k)   // pad 100..127
                sHWb[e0r * HSTRIDE + k] = __float2bfloat16(0.f);
        }
        __syncthreads();

        // ---- phase 1: A-fragment loads (wave's 16 edges)
        short8 afrag[4];
#pragma unroll
        for (int kt = 0; kt < 4; ++kt)
            afrag[kt] = *(const short8*)&sHW[(wbase + m16) * HSTRIDE + kt * 32 + quad * 8];
        __syncthreads();

        // ---- phase 2: GEMM w = h @ W2, C (bf16) into sHW rows
#pragma unroll
        for (int t = 0; t < 12; ++t) {
            f32x4 acc = {0.f, 0.f, 0.f, 0.f};
#pragma unroll
            for (int kt = 0; kt < 4; ++kt) {
                short8 bfrag = *(const short8*)&sW2B[(((t * 4) + kt) * 64 + lane) * 8];
                acc = __builtin_amdgcn_mfma_f32_16x16x32_bf16(afrag[kt], bfrag, acc, 0, 0, 0);
            }
#pragma unroll
            for (int r = 0; r < 4; ++r) {
                int er = wbase + quad * 4 + r;
                sHWb[er * WSTRIDE + t * 16 + m16] = __float2bfloat16(acc[r]);
            }
        }
        __syncthreads();

        // ---- phase 3: run-aggregated messages + pk-bf16 atomic scatter
        float A0 = 0.f, A1x = 0.f, A1y = 0.f, A1z = 0.f;
        float A2x = 0.f, A2y = 0.f, A2z = 0.f, A3 = 0.f;
        int cur_dst = -1;
        for (int i = 0; i < 16; ++i) {
            int elc = wbase + i;
            int dst = sDst[elc];                   // wave-uniform (LDS)
            if (dst != cur_dst) {
                flush_acc(s_table, cur_dst, lane, A0, A1x, A1y, A1z, A2x, A2y, A2z, A3);
                A0 = A1x = A1y = A1z = A2x = A2y = A2z = A3 = 0.f;
                cur_dst = dst;
            }
            int src = sSrc[elc];
            float e0  = sAttr[elc * 4 + 0];
            float e1x = sAttr[elc * 4 + 1];
            float e1y = sAttr[elc * 4 + 2];
            float e1z = sAttr[elc * 4 + 3];

            const T* lrow = l_table + (size_t)src * 160;
            float y0 = ldv(lrow, lane);
            float w_a = b2f(sHWb[elc * WSTRIDE + lane]);
            float w_b = b2f(sHWb[elc * WSTRIDE + 64 + lane]);

            A0 += w_a * y0 * e0;                       // m0
            float m1b = w_b * y0;                      // m1
            A1x += m1b * e1x; A1y += m1b * e1y; A1z += m1b * e1z;
            if (lane < 32) {
                float w_c = b2f(sHWb[elc * WSTRIDE + 128 + lane]);
                float w3v = b2f(sHWb[elc * WSTRIDE + 160 + lane]);
                float y1x = ldv(lrow, 64 + lane * 3 + 0);
                float y1y = ldv(lrow, 64 + lane * 3 + 1);
                float y1z = ldv(lrow, 64 + lane * 3 + 2);
                float g = w_c * e0;                    // m2
                A2x += g * y1x; A2y += g * y1y; A2z += g * y1z;
                float dot = y1x * e1x + y1y * e1y + y1z * e1z;
                A3 += w3v * dot * 0.5773502691896258f; // m3
            }
        }
        flush_acc(s_table, cur_dst, lane, A0, A1x, A1y, A1z, A2x, A2y, A2z, A3);
        __syncthreads();   // sHW + metadata reads done before next tile
    }
    asm volatile("s_waitcnt vmcnt(0)" ::: "memory");   // drain asm atomics
}

__global__ __launch_bounds__(256) void edge_kernel(
    const void* edge_attr, const void* el, const void* W_fc1, const void* W_fc2,
    const int* edge_src, const int* edge_dst, const int* sorted_idx,
    const void* l_table, __hip_bfloat16* s_table, const void* node_attr)
{
    __shared__ __hip_bfloat16 sW1[NBASIS * NRADIAL];   // 2000 B
    __shared__ short sW2B[12 * 4 * 64 * 8];            // 49152 B
    __shared__ short sHW[64 * WSTRIDE];                // 25600 B (h / w union)
    __shared__ int sSrc[64], sDst[64];                 // 512 B
    __shared__ float sAttr[256];                       // 1024 B
    if (input_is_f32(node_attr))
        edge_body<float>((const float*)edge_attr, (const float*)el,
                         (const float*)W_fc1, (const float*)W_fc2,
                         edge_src, edge_dst, sorted_idx,
                         (const float*)l_table, s_table,
                         sW1, sW2B, sHW, sSrc, sDst, sAttr);
    else
        edge_body<__hip_bfloat16>((const __hip_bfloat16*)edge_attr,
                                  (const __hip_bfloat16*)el,
                                  (const __hip_bfloat16*)W_fc1,
                                  (const __hip_bfloat16*)W_fc2,
                                  edge_src, edge_dst, sorted_idx,
                                  (const __hip_bfloat16*)l_table, s_table,
                                  sW1, sW2B, sHW, sSrc, sDst, sAttr);
}

// ---------------------------------------------------------------------------
// Kernel 3: output. Per-node W_l2 mixes of bf16 s_table + self-interaction.
// ---------------------------------------------------------------------------
template <class T>
__device__ __forceinline__ void output_body(
    const T* __restrict__ node_input, const T* __restrict__ node_attr,
    const T* __restrict__ W_si0, const T* __restrict__ W_si1,
    const T* __restrict__ W_l2_00, const T* __restrict__ W_l2_10,
    const T* __restrict__ W_l2_01, const T* __restrict__ W_l2_11,
    const __hip_bfloat16* __restrict__ s_table, T* __restrict__ out)
{
    int wave = (blockIdx.x * 256 + threadIdx.x) >> 6;
    int lane = threadIdx.x & 63;
    if (wave >= N_NODES) return;
    const int n = wave;
    float a = ldv(node_attr, n);
    const T* xrow = node_input + (size_t)n * 160;
    const __hip_bfloat16* srow = s_table + (size_t)n * 384;

    float si = 0.f, o = 0.f;
    for (int u = 0; u < 64; ++u) {
        si += ldv(xrow, u) * ldv(W_si0, u * 64 + lane);
        o += b2f(srow[u]) * ldv(W_l2_00, u * 64 + lane);
    }
    for (int u = 0; u < 32; ++u)
        o += b2f(srow[352 + u]) * ldv(W_l2_10, u * 64 + lane);

    // 0.5 (skip-mix) * 0.25 (1/sqrt(16)) / sqrt(96)
    const float OC = 0.5f * 0.25f / 9.797958971132712f;
    stv(out, (size_t)n * 160 + lane, si * a * 0.125f + o * a * OC);

    if (lane < 32) {
        float sid[3] = {0.f, 0.f, 0.f}, od[3] = {0.f, 0.f, 0.f};
        for (int u = 0; u < 32; ++u) {
            float wsi = ldv(W_si1, u * 32 + lane);
            float wl2 = ldv(W_l2_11, u * 32 + lane);
#pragma unroll
            for (int d = 0; d < 3; ++d) {
                sid[d] += ldv(xrow, 64 + u * 3 + d) * wsi;
                od[d] += b2f(srow[256 + d * 32 + u]) * wl2;   // s2 planes
            }
        }
        for (int u = 0; u < 64; ++u) {
            float wl2 = ldv(W_l2_01, u * 32 + lane);
#pragma unroll
            for (int d = 0; d < 3; ++d)
                od[d] += b2f(srow[64 + d * 64 + u]) * wl2;    // s1 planes
        }
        const float SI1 = a * 0.17677669529663687f;
#pragma unroll
        for (int d = 0; d < 3; ++d)
            stv(out, (size_t)n * 160 + 64 + lane * 3 + d, sid[d] * SI1 + od[d] * a * OC);
    }
}

__global__ __launch_bounds__(256) void output_kernel(
    const void* node_input, const void* node_attr,
    const void* W_si0, const void* W_si1,
    const void* W_l2_00, const void* W_l2_10,
    const void* W_l2_01, const void* W_l2_11,
    const __hip_bfloat16* s_table, void* out)
{
    if (input_is_f32(node_attr))
        output_body<float>((const float*)node_input, (const float*)node_attr,
                           (const float*)W_si0, (const float*)W_si1,
                           (const float*)W_l2_00, (const float*)W_l2_10,
                           (const float*)W_l2_01, (const float*)W_l2_11,
                           s_table, (float*)out);
    else
        output_body<__hip_bfloat16>((const __hip_bfloat16*)node_input,
                                    (const __hip_bfloat16*)node_attr,
                                    (const __hip_bfloat16*)W_si0,
                                    (const __hip_bfloat16*)W_si1,
                                    (const __hip_bfloat16*)W_l2_00,
                                    (const __hip_bfloat16*)W_l2_10,
                                    (const __hip_bfloat16*)W_l2_01,
                                    (const __hip_bfloat16*)W_l2_11,
                                    s_table, (__hip_bfloat16*)out);
}

extern "C" void kernel_launch(void* const* d_in, const int* in_sizes, int n_in,
                              void* d_out, int out_size, void* d_ws, size_t ws_size,
                              hipStream_t stream)
{
    const void* node_input = d_in[0];
    const void* node_attr  = d_in[1];
    const void* edge_attr  = d_in[2];
    const void* el         = d_in[3];
    const void* W_si0  = d_in[4];
    const void* W_si1  = d_in[5];
    const void* W_l1_0 = d_in[6];
    const void* W_l1_1 = d_in[7];
    const void* W_l2_00 = d_in[8];
    const void* W_l2_10 = d_in[9];
    const void* W_l2_01 = d_in[10];
    const void* W_l2_11 = d_in[11];
    const void* W_fc1  = d_in[12];
    const void* W_fc2  = d_in[13];
    const int* edge_src = (const int*)d_in[14];
    const int* edge_dst = (const int*)d_in[15];

    // ws layout: s_table bf16 (N*384*2 = 38.4 MB) | sorted_idx (3.2 MB) | counts (0.2 MB)
    __hip_bfloat16* s_table = (__hip_bfloat16*)d_ws;
    int* sorted_idx = (int*)((char*)d_ws + (size_t)N_NODES * 384 * 2);
    int* counts     = (int*)((char*)sorted_idx + (size_t)N_EDGES * 4);
    void* l_table = d_out;   // N*160 elements, overwritten by output_kernel

    size_t ws_used = (size_t)N_NODES * 384 * 2 + (size_t)N_EDGES * 4 + (size_t)N_NODES * 4;
    hipMemsetAsync(d_ws, 0, ws_used, stream);

    hist_kernel<<<(N_EDGES + 255) / 256, 256, 0, stream>>>(edge_dst, counts);
    scan_kernel<<<1, 1024, 0, stream>>>(counts);
    scatter_kernel<<<(N_EDGES + 255) / 256, 256, 0, stream>>>(edge_dst, counts, sorted_idx);

    node_linear_kernel<<<(N_NODES + 3) / 4, 256, 0, stream>>>(
        node_input, node_attr, W_l1_0, W_l1_1, l_table);
    edge_kernel<<<EDGE_GRID, 256, 0, stream>>>(
        edge_attr, el, W_fc1, W_fc2, edge_src, edge_dst, sorted_idx,
        l_table, s_table, node_attr);
    output_kernel<<<(N_NODES + 3) / 4, 256, 0, stream>>>(
        node_input, node_attr, W_si0, W_si1, W_l2_00, W_l2_10, W_l2_01, W_l2_11,
        s_table, d_out);
}